// Round 12
// baseline (95.609 us; speedup 1.0000x reference)
//
#include <hip/hip_runtime.h>
#include <hip/hip_bf16.h>

// Problem constants (match reference setup_inputs)
#define BB 64
#define SS 512
#define DD 1024
#define VV 64
#define NSEG (BB * SS)        // 32768
#define THREADS 512
#define WPB (THREADS / 64)    // 8 waves per block, one segment per wave
#define GRID (NSEG / WPB)     // 4096 blocks
#define REPS 3                // DIAGNOSTIC: make main dispatch visible in top-5 PMC

typedef float f32x4 __attribute__((ext_vector_type(4)));

// ---------- Pass A: segment start offsets from sorted segment_ids ----------
__global__ __launch_bounds__(256) void fill_bounds_kernel(
    const int* __restrict__ seg_ids,
    int* __restrict__ seg_start,
    int T)
{
    int t = blockIdx.x * blockDim.x + threadIdx.x;
    if (t >= T) return;
    int cur  = seg_ids[t];
    int prev = (t == 0) ? -1 : seg_ids[t - 1];
    for (int s = prev + 1; s <= cur; ++s) seg_start[s] = t;
    if (t == T - 1) {
        for (int s = cur + 1; s <= NSEG; ++s) seg_start[s] = T;
    }
}

// ---------- Pass B (DIAGNOSTIC): R10 wave-per-segment body repeated 3x ----------
// Idempotent: every rep recomputes and re-stores identical values. The asm
// memory clobber between reps prevents load-CSE and dead-store elimination,
// so each rep issues the full load+store traffic (rule #17: keep work live).
__global__ __launch_bounds__(THREADS) void seg_mean_wps_diag_kernel(
    const int* __restrict__ tokens,
    const int* __restrict__ seg_start,  // [NSEG+1]
    const float* __restrict__ emb,      // [V, D]
    const float* __restrict__ pos,      // [S, D]
    float* __restrict__ out)            // [B*S, D]
{
    const int wave = threadIdx.x >> 6;
    const int lane = threadIdx.x & 63;
    const int seg  = blockIdx.x * WPB + wave;
    const int d0   = lane * 4;

    #pragma unroll 1
    for (int rep = 0; rep < REPS; ++rep) {
        asm volatile("" ::: "memory");   // no CSE/DSE across reps

        const int lo = seg_start[seg];
        const int hi = seg_start[seg + 1];

        const float* prow = pos + (size_t)(seg & (SS - 1)) * DD + d0;
        f32x4 p0 = *reinterpret_cast<const f32x4*>(prow);
        f32x4 p1 = *reinterpret_cast<const f32x4*>(prow + 256);
        f32x4 p2 = *reinterpret_cast<const f32x4*>(prow + 512);
        f32x4 p3 = *reinterpret_cast<const f32x4*>(prow + 768);

        f32x4 a0 = (f32x4)(0.f), a1 = (f32x4)(0.f), a2 = (f32x4)(0.f), a3 = (f32x4)(0.f);
        for (int t = lo; t < hi; ++t) {
            const int tok = tokens[t];               // uniform across wave
            const float* erow = emb + (size_t)tok * DD + d0;
            a0 += *reinterpret_cast<const f32x4*>(erow);
            a1 += *reinterpret_cast<const f32x4*>(erow + 256);
            a2 += *reinterpret_cast<const f32x4*>(erow + 512);
            a3 += *reinterpret_cast<const f32x4*>(erow + 768);
        }

        const int cnt = hi - lo;
        const float inv = (cnt > 0) ? (1.0f / (float)cnt) : 0.0f;

        f32x4 o0 = a0 * inv + p0;
        f32x4 o1 = a1 * inv + p1;
        f32x4 o2 = a2 * inv + p2;
        f32x4 o3 = a3 * inv + p3;

        float* orow = out + (size_t)seg * DD + d0;
        __builtin_nontemporal_store(o0, reinterpret_cast<f32x4*>(orow));
        __builtin_nontemporal_store(o1, reinterpret_cast<f32x4*>(orow + 256));
        __builtin_nontemporal_store(o2, reinterpret_cast<f32x4*>(orow + 512));
        __builtin_nontemporal_store(o3, reinterpret_cast<f32x4*>(orow + 768));
    }
}

// ---------- Fallback (ws too small): binary-search kernel ----------
__device__ __forceinline__ int lower_bound_dev(const int* __restrict__ a, int n, int key) {
    int lo = 0, hi = n;
    while (lo < hi) {
        int mid = (lo + hi) >> 1;
        if (a[mid] < key) lo = mid + 1; else hi = mid;
    }
    return lo;
}

__global__ __launch_bounds__(256) void seg_mean_embed_bsearch_kernel(
    const int* __restrict__ tokens,
    const int* __restrict__ seg_ids,
    const float* __restrict__ emb,
    const float* __restrict__ pos,
    float* __restrict__ out,
    int T)
{
    const int seg = blockIdx.x;
    const int lo = lower_bound_dev(seg_ids, T, seg);
    const int hi = lower_bound_dev(seg_ids, T, seg + 1);
    const int d = threadIdx.x * 4;

    f32x4 acc = (f32x4)(0.f);
    for (int t = lo; t < hi; ++t) {
        const int tok = tokens[t];
        acc += *reinterpret_cast<const f32x4*>(emb + (size_t)tok * DD + d);
    }
    const int cnt = hi - lo;
    const float inv = (cnt > 0) ? (1.0f / (float)cnt) : 0.0f;
    const int s = seg & (SS - 1);
    const f32x4 p = *reinterpret_cast<const f32x4*>(pos + (size_t)s * DD + d);
    f32x4 o = acc * inv + p;
    *reinterpret_cast<f32x4*>(out + (size_t)seg * DD + d) = o;
}

extern "C" void kernel_launch(void* const* d_in, const int* in_sizes, int n_in,
                              void* d_out, int out_size, void* d_ws, size_t ws_size,
                              hipStream_t stream) {
    const int*   tokens  = (const int*)d_in[0];
    const int*   seg_ids = (const int*)d_in[1];
    const float* emb     = (const float*)d_in[2];
    const float* pos     = (const float*)d_in[3];
    float*       out     = (float*)d_out;
    const int T = in_sizes[0];

    const size_t need = (size_t)(NSEG + 1) * sizeof(int);
    if (ws_size >= need) {
        int* seg_start = (int*)d_ws;
        fill_bounds_kernel<<<(T + 255) / 256, 256, 0, stream>>>(seg_ids, seg_start, T);
        seg_mean_wps_diag_kernel<<<GRID, THREADS, 0, stream>>>(tokens, seg_start, emb, pos, out);
    } else {
        seg_mean_embed_bsearch_kernel<<<NSEG, 256, 0, stream>>>(tokens, seg_ids, emb, pos, out, T);
    }
}

// Round 13
// 42.082 us; speedup vs baseline: 2.2720x; 2.2720x over previous
//
#include <hip/hip_runtime.h>
#include <hip/hip_bf16.h>

// Problem constants (match reference setup_inputs)
#define BB 64
#define SS 512
#define DD 1024
#define VV 64
#define NSEG (BB * SS)        // 32768
#define THREADS 512
#define WPB (THREADS / 64)    // 8 waves per block, one segment per wave
#define GRID (NSEG / WPB)     // 4096 blocks

typedef float f32x4 __attribute__((ext_vector_type(4)));

// ---------- Pass A: segment start offsets from sorted segment_ids ----------
__global__ __launch_bounds__(256) void fill_bounds_kernel(
    const int* __restrict__ seg_ids,
    int* __restrict__ seg_start,
    int T)
{
    int t = blockIdx.x * blockDim.x + threadIdx.x;
    if (t >= T) return;
    int cur  = seg_ids[t];
    int prev = (t == 0) ? -1 : seg_ids[t - 1];
    for (int s = prev + 1; s <= cur; ++s) seg_start[s] = t;
    if (t == T - 1) {
        for (int s = cur + 1; s <= NSEG; ++s) seg_start[s] = T;
    }
}

// ---------- Pass B: wave-per-segment gather, PLAIN stores ----------
// Single variable vs R10: stores go through L2 (write-back) instead of NT.
// Theory: wave gets store-ack at L2 -> short drain at endpgm -> shorter block
// lifetime -> higher store duty cycle (memset: 6.9 TB/s at 10% occupancy with
// plain stores; our NT path measured 3.5 TB/s at 53% occupancy in R12).
__global__ __launch_bounds__(THREADS) void seg_mean_wps_plain_kernel(
    const int* __restrict__ tokens,
    const int* __restrict__ seg_start,  // [NSEG+1]
    const float* __restrict__ emb,      // [V, D]
    const float* __restrict__ pos,      // [S, D]
    float* __restrict__ out)            // [B*S, D]
{
    const int wave = threadIdx.x >> 6;
    const int lane = threadIdx.x & 63;
    const int seg  = blockIdx.x * WPB + wave;
    const int d0   = lane * 4;

    const int lo = seg_start[seg];
    const int hi = seg_start[seg + 1];

    // pos loads are independent of the gather chain -> issue first
    const float* prow = pos + (size_t)(seg & (SS - 1)) * DD + d0;
    f32x4 p0 = *reinterpret_cast<const f32x4*>(prow);
    f32x4 p1 = *reinterpret_cast<const f32x4*>(prow + 256);
    f32x4 p2 = *reinterpret_cast<const f32x4*>(prow + 512);
    f32x4 p3 = *reinterpret_cast<const f32x4*>(prow + 768);

    f32x4 a0 = (f32x4)(0.f), a1 = (f32x4)(0.f), a2 = (f32x4)(0.f), a3 = (f32x4)(0.f);
    for (int t = lo; t < hi; ++t) {
        const int tok = tokens[t];               // uniform across wave
        const float* erow = emb + (size_t)tok * DD + d0;
        a0 += *reinterpret_cast<const f32x4*>(erow);
        a1 += *reinterpret_cast<const f32x4*>(erow + 256);
        a2 += *reinterpret_cast<const f32x4*>(erow + 512);
        a3 += *reinterpret_cast<const f32x4*>(erow + 768);
    }

    const int cnt = hi - lo;
    const float inv = (cnt > 0) ? (1.0f / (float)cnt) : 0.0f;

    f32x4 o0 = a0 * inv + p0;
    f32x4 o1 = a1 * inv + p1;
    f32x4 o2 = a2 * inv + p2;
    f32x4 o3 = a3 * inv + p3;

    float* orow = out + (size_t)seg * DD + d0;
    *reinterpret_cast<f32x4*>(orow)       = o0;
    *reinterpret_cast<f32x4*>(orow + 256) = o1;
    *reinterpret_cast<f32x4*>(orow + 512) = o2;
    *reinterpret_cast<f32x4*>(orow + 768) = o3;
}

// ---------- Fallback (ws too small): binary-search kernel ----------
__device__ __forceinline__ int lower_bound_dev(const int* __restrict__ a, int n, int key) {
    int lo = 0, hi = n;
    while (lo < hi) {
        int mid = (lo + hi) >> 1;
        if (a[mid] < key) lo = mid + 1; else hi = mid;
    }
    return lo;
}

__global__ __launch_bounds__(256) void seg_mean_embed_bsearch_kernel(
    const int* __restrict__ tokens,
    const int* __restrict__ seg_ids,
    const float* __restrict__ emb,
    const float* __restrict__ pos,
    float* __restrict__ out,
    int T)
{
    const int seg = blockIdx.x;
    const int lo = lower_bound_dev(seg_ids, T, seg);
    const int hi = lower_bound_dev(seg_ids, T, seg + 1);
    const int d = threadIdx.x * 4;

    f32x4 acc = (f32x4)(0.f);
    for (int t = lo; t < hi; ++t) {
        const int tok = tokens[t];
        acc += *reinterpret_cast<const f32x4*>(emb + (size_t)tok * DD + d);
    }
    const int cnt = hi - lo;
    const float inv = (cnt > 0) ? (1.0f / (float)cnt) : 0.0f;
    const int s = seg & (SS - 1);
    const f32x4 p = *reinterpret_cast<const f32x4*>(pos + (size_t)s * DD + d);
    f32x4 o = acc * inv + p;
    *reinterpret_cast<f32x4*>(out + (size_t)seg * DD + d) = o;
}

extern "C" void kernel_launch(void* const* d_in, const int* in_sizes, int n_in,
                              void* d_out, int out_size, void* d_ws, size_t ws_size,
                              hipStream_t stream) {
    const int*   tokens  = (const int*)d_in[0];
    const int*   seg_ids = (const int*)d_in[1];
    const float* emb     = (const float*)d_in[2];
    const float* pos     = (const float*)d_in[3];
    float*       out     = (float*)d_out;
    const int T = in_sizes[0];

    const size_t need = (size_t)(NSEG + 1) * sizeof(int);
    if (ws_size >= need) {
        int* seg_start = (int*)d_ws;
        fill_bounds_kernel<<<(T + 255) / 256, 256, 0, stream>>>(seg_ids, seg_start, T);
        seg_mean_wps_plain_kernel<<<GRID, THREADS, 0, stream>>>(tokens, seg_start, emb, pos, out);
    } else {
        seg_mean_embed_bsearch_kernel<<<NSEG, 256, 0, stream>>>(tokens, seg_ids, emb, pos, out, T);
    }
}

// Round 14
// 34.803 us; speedup vs baseline: 2.7472x; 1.2092x over previous
//
#include <hip/hip_runtime.h>
#include <hip/hip_bf16.h>

// Problem constants (match reference setup_inputs)
#define BB 64
#define SS 512
#define DD 1024
#define VV 64
#define NSEG (BB * SS)        // 32768
#define THREADS 512
#define WPB (THREADS / 64)    // 8 waves per block, one segment per wave
#define GRID (NSEG / WPB)     // 4096 blocks: blockIdx = (bgroup<<9) | s

typedef float f32x4 __attribute__((ext_vector_type(4)));

// ---------- Pass A: segment start offsets from sorted segment_ids ----------
__global__ __launch_bounds__(256) void fill_bounds_kernel(
    const int* __restrict__ seg_ids,
    int* __restrict__ seg_start,
    int T)
{
    int t = blockIdx.x * blockDim.x + threadIdx.x;
    if (t >= T) return;
    int cur  = seg_ids[t];
    int prev = (t == 0) ? -1 : seg_ids[t - 1];
    for (int s = prev + 1; s <= cur; ++s) seg_start[s] = t;
    if (t == T - 1) {
        for (int s = cur + 1; s <= NSEG; ++s) seg_start[s] = T;
    }
}

// ---------- Pass B: wave-per-segment, scalar-pipe control loads, LDS pos ----------
// Theory: limiter is VMEM vector-instruction rate (~24-30/segment across all
// prior nulls). Cut to ~20/seg: seg forced into SGPR -> seg_start/tokens become
// s_load (scalar K$ pipe, lgkmcnt); pos shared per-block via LDS (all 8 waves
// have the same s). Remaining VMEM: 16 gather + 4 NT store (+0.5 amortized
// pos staging).
__global__ __launch_bounds__(THREADS) void seg_mean_sload_kernel(
    const int* __restrict__ tokens,
    const int* __restrict__ seg_start,  // [NSEG+1]
    const float* __restrict__ emb,      // [V, D]
    const float* __restrict__ pos,      // [S, D]
    float* __restrict__ out)            // [B*S, D]
{
    __shared__ float s_pos[DD];         // 4 KB: the block's shared pos row

    const int tid = threadIdx.x;
    const int bg  = blockIdx.x >> 9;    // 0..7  (b-group of 8 batches)
    const int s   = blockIdx.x & (SS - 1);

    // stage pos[s] once per block (4 VMEM instrs per 8 segments)
    if (tid < DD / 4) {
        reinterpret_cast<f32x4*>(s_pos)[tid] =
            reinterpret_cast<const f32x4*>(pos + (size_t)s * DD)[tid];
    }
    __syncthreads();

    const int wave = tid >> 6;
    const int lane = tid & 63;
    // seg is wave-uniform; readfirstlane pins it to an SGPR so that
    // seg_start[...] and tokens[...] compile to s_load (scalar pipe, 0 VMEM).
    const int seg = __builtin_amdgcn_readfirstlane((bg * WPB + wave) * SS + s);
    const int d0  = lane * 4;

    const int lo = seg_start[seg];
    const int hi = seg_start[seg + 1];

    f32x4 a0 = (f32x4)(0.f), a1 = (f32x4)(0.f), a2 = (f32x4)(0.f), a3 = (f32x4)(0.f);
    for (int t = lo; t < hi; ++t) {
        const int tok = tokens[t];               // SGPR index -> s_load (K$ hit)
        const float* erow = emb + (size_t)tok * DD + d0;
        a0 += *reinterpret_cast<const f32x4*>(erow);
        a1 += *reinterpret_cast<const f32x4*>(erow + 256);
        a2 += *reinterpret_cast<const f32x4*>(erow + 512);
        a3 += *reinterpret_cast<const f32x4*>(erow + 768);
    }

    const int cnt = hi - lo;
    const float inv = (cnt > 0) ? (1.0f / (float)cnt) : 0.0f;

    // pos from LDS (ds_read, lgkm pipe — no VMEM)
    const f32x4 p0 = *reinterpret_cast<const f32x4*>(s_pos + d0);
    const f32x4 p1 = *reinterpret_cast<const f32x4*>(s_pos + d0 + 256);
    const f32x4 p2 = *reinterpret_cast<const f32x4*>(s_pos + d0 + 512);
    const f32x4 p3 = *reinterpret_cast<const f32x4*>(s_pos + d0 + 768);

    f32x4 o0 = a0 * inv + p0;
    f32x4 o1 = a1 * inv + p1;
    f32x4 o2 = a2 * inv + p2;
    f32x4 o3 = a3 * inv + p3;

    float* orow = out + (size_t)seg * DD + d0;
    __builtin_nontemporal_store(o0, reinterpret_cast<f32x4*>(orow));
    __builtin_nontemporal_store(o1, reinterpret_cast<f32x4*>(orow + 256));
    __builtin_nontemporal_store(o2, reinterpret_cast<f32x4*>(orow + 512));
    __builtin_nontemporal_store(o3, reinterpret_cast<f32x4*>(orow + 768));
}

// ---------- Fallback (ws too small): binary-search kernel ----------
__device__ __forceinline__ int lower_bound_dev(const int* __restrict__ a, int n, int key) {
    int lo = 0, hi = n;
    while (lo < hi) {
        int mid = (lo + hi) >> 1;
        if (a[mid] < key) lo = mid + 1; else hi = mid;
    }
    return lo;
}

__global__ __launch_bounds__(256) void seg_mean_embed_bsearch_kernel(
    const int* __restrict__ tokens,
    const int* __restrict__ seg_ids,
    const float* __restrict__ emb,
    const float* __restrict__ pos,
    float* __restrict__ out,
    int T)
{
    const int seg = blockIdx.x;
    const int lo = lower_bound_dev(seg_ids, T, seg);
    const int hi = lower_bound_dev(seg_ids, T, seg + 1);
    const int d = threadIdx.x * 4;

    f32x4 acc = (f32x4)(0.f);
    for (int t = lo; t < hi; ++t) {
        const int tok = tokens[t];
        acc += *reinterpret_cast<const f32x4*>(emb + (size_t)tok * DD + d);
    }
    const int cnt = hi - lo;
    const float inv = (cnt > 0) ? (1.0f / (float)cnt) : 0.0f;
    const int s = seg & (SS - 1);
    const f32x4 p = *reinterpret_cast<const f32x4*>(pos + (size_t)s * DD + d);
    f32x4 o = acc * inv + p;
    *reinterpret_cast<f32x4*>(out + (size_t)seg * DD + d) = o;
}

extern "C" void kernel_launch(void* const* d_in, const int* in_sizes, int n_in,
                              void* d_out, int out_size, void* d_ws, size_t ws_size,
                              hipStream_t stream) {
    const int*   tokens  = (const int*)d_in[0];
    const int*   seg_ids = (const int*)d_in[1];
    const float* emb     = (const float*)d_in[2];
    const float* pos     = (const float*)d_in[3];
    float*       out     = (float*)d_out;
    const int T = in_sizes[0];

    const size_t need = (size_t)(NSEG + 1) * sizeof(int);
    if (ws_size >= need) {
        int* seg_start = (int*)d_ws;
        fill_bounds_kernel<<<(T + 255) / 256, 256, 0, stream>>>(seg_ids, seg_start, T);
        seg_mean_sload_kernel<<<GRID, THREADS, 0, stream>>>(tokens, seg_start, emb, pos, out);
    } else {
        seg_mean_embed_bsearch_kernel<<<NSEG, 256, 0, stream>>>(tokens, seg_ids, emb, pos, out, T);
    }
}